// Round 14
// baseline (47.016 us; speedup 1.0000x reference)
//
#include <hip/hip_runtime.h>

#define COLS   8192
#define LEVELS 8
#define TPB    512
#define RPB    2     // rows per block

typedef float f4_t __attribute__((ext_vector_type(4)));

__device__ __forceinline__ void nt_store4(float* p, const float4 v) {
    f4_t w; w.x = v.x; w.y = v.y; w.z = v.z; w.w = v.w;
    __builtin_nontemporal_store(w, reinterpret_cast<f4_t*>(p));
}

// LDS-only barrier: waits LDS ops, lets global (vmcnt) stores stay in flight.
__device__ __forceinline__ void bar_lds() {
    asm volatile("s_waitcnt lgkmcnt(0)" ::: "memory");
    __builtin_amdgcn_sched_barrier(0);
    __builtin_amdgcn_s_barrier();
    __builtin_amdgcn_sched_barrier(0);
}

// TWO rows per block: every phase does both rows' work (independent LDS
// slices) before its barrier -> phase-boundary stalls per row halve, and
// each phase has 2x independent memory ops to overlap. Tail runs on waves
// 0 and 1 concurrently (one row each). nt stores for never-re-read streams.
__global__ __launch_bounds__(TPB, 4) void despawn_kernel(
    const float* __restrict__ x, const float* __restrict__ scaling,
    float* __restrict__ out, int rows)
{
    __shared__ __align__(16) float B[RPB][4096];   // 32 KB
    __shared__ __align__(16) float C[RPB][2048];   // 16 KB
    __shared__ __align__(16) float D[RPB][2048];   // 16 KB
    __shared__ float filt[LEVELS * 4];

    const int tid = threadIdx.x;
    if (tid < LEVELS * 4) filt[tid] = scaling[tid];
    bar_lds();

    const size_t row0 = (size_t)blockIdx.x * RPB;
    const size_t cbase = (size_t)rows * COLS;

    // ---------------- analysis level 0 (both rows, then barrier) ------------
    {
        const float h0 = filt[0], h1 = filt[1], h2 = filt[2], h3 = filt[3];
        const float g0 = h3, g1 = -h2, g2 = h1, g3 = -h0;
        const int q8 = COLS / 8, qm = COLS / 4 - 1;
        #pragma unroll
        for (int r = 0; r < RPB; ++r) {
            const float4* __restrict__ xg4 =
                reinterpret_cast<const float4*>(x + (row0 + r) * COLS);
            float* __restrict__ oc = out + cbase + (row0 + r) * COLS;
            for (int i = tid; i < q8; i += TPB) {
                const float4 va = xg4[(2 * i - 1) & qm];
                const float4 vb = xg4[2 * i];
                const float4 vc = xg4[2 * i + 1];
                float4 dv, av;
                dv.x = g0*vb.x + g1*va.w + g2*va.z + g3*va.y;
                av.x = h0*vb.x + h1*va.w + h2*va.z + h3*va.y;
                dv.y = g0*vb.z + g1*vb.y + g2*vb.x + g3*va.w;
                av.y = h0*vb.z + h1*vb.y + h2*vb.x + h3*va.w;
                dv.z = g0*vc.x + g1*vb.w + g2*vb.z + g3*vb.y;
                av.z = h0*vc.x + h1*vb.w + h2*vb.z + h3*vb.y;
                dv.w = g0*vc.z + g1*vc.y + g2*vc.x + g3*vb.w;
                av.w = h0*vc.z + h1*vc.y + h2*vc.x + h3*vb.w;
                reinterpret_cast<float4*>(oc)[i]   = dv;   // d0: CACHED (re-read)
                reinterpret_cast<float4*>(B[r])[i] = av;
            }
        }
        bar_lds();
    }

    // ---------------- analysis levels 1..3 ---------------------------------
    {
        int n = COLS / 2, coff = COLS / 2, dOff = 0;
        float* cur[RPB] = { B[0], B[1] };
        float* nxt[RPB] = { C[0], C[1] };
        for (int lev = 1; lev <= 3; ++lev) {
            const float h0 = filt[4*lev+0], h1 = filt[4*lev+1],
                        h2 = filt[4*lev+2], h3 = filt[4*lev+3];
            const float g0 = h3, g1 = -h2, g2 = h1, g3 = -h0;
            const int half = n >> 1, qq = half >> 2, qm = (n >> 2) - 1;
            const bool toD = (lev >= 2);
            #pragma unroll
            for (int r = 0; r < RPB; ++r) {
                const float4* c4 = reinterpret_cast<const float4*>(cur[r]);
                float* ob = out + cbase + (row0 + r) * COLS + coff;
                float4* n4 = reinterpret_cast<float4*>(nxt[r]);
                float4* D4 = reinterpret_cast<float4*>(D[r] + dOff);
                for (int p = tid; p < qq; p += TPB) {
                    const float4 va = c4[(2 * p - 1) & qm];
                    const float4 vb = c4[2 * p];
                    const float4 vc = c4[2 * p + 1];
                    float4 dv, av;
                    dv.x = g0*vb.x + g1*va.w + g2*va.z + g3*va.y;
                    av.x = h0*vb.x + h1*va.w + h2*va.z + h3*va.y;
                    dv.y = g0*vb.z + g1*vb.y + g2*vb.x + g3*va.w;
                    av.y = h0*vb.z + h1*vb.y + h2*vb.x + h3*va.w;
                    dv.z = g0*vc.x + g1*vb.w + g2*vb.z + g3*vb.y;
                    av.z = h0*vc.x + h1*vb.w + h2*vb.z + h3*vb.y;
                    dv.w = g0*vc.z + g1*vc.y + g2*vc.x + g3*vb.w;
                    av.w = h0*vc.z + h1*vc.y + h2*vc.x + h3*vb.w;
                    if (toD) {
                        nt_store4(ob + 4*p, dv);   // d2/d3: never re-read
                        D4[p] = dv;
                    } else {
                        reinterpret_cast<float4*>(ob)[p] = dv;  // d1: CACHED
                    }
                    n4[p] = av;
                }
            }
            bar_lds();
            coff += half;
            if (toD) dOff += half;
            n = half;
            #pragma unroll
            for (int r = 0; r < RPB; ++r) { float* t = cur[r]; cur[r] = nxt[r]; nxt[r] = t; }
        }
    }
    // per row: a3(512) in C[r], d2 in D[r][0..1024), d3 in D[r][1024..1536)

    // ---------------- tail: wave w handles row w (concurrent) --------------
    // D layout: d2@0(1024) d3@1024(512) d4@1536(256) d5@1792(128)
    //           d6@1920(64) d7@1984(32) approx@2016(32)
    {
        const int w = tid >> 6, lane = tid & 63;
        if (w < RPB) {
            const int r = w;
            float* Br = B[r]; float* Cr = C[r]; float* Dr = D[r];
            float* __restrict__ oc = out + cbase + (row0 + r) * COLS;
            float* acur = Cr;
            float* anxt = Br;
            int nn = 512, coffW = 7680, dW = 1536;
            for (int lev = 4; lev <= 7; ++lev) {
                const float h0 = filt[4*lev+0], h1 = filt[4*lev+1],
                            h2 = filt[4*lev+2], h3 = filt[4*lev+3];
                const float g0 = h3, g1 = -h2, g2 = h1, g3 = -h0;
                const int half = nn >> 1, mask = nn - 1;
                for (int i = lane; i < half; i += 64) {
                    const int b = 2 * i;
                    const float x0 = acur[b];
                    const float x1 = acur[(b - 1) & mask];
                    const float x2 = acur[(b - 2) & mask];
                    const float x3 = acur[(b - 3) & mask];
                    const float d = g0*x0 + g1*x1 + g2*x2 + g3*x3;
                    const float a = h0*x0 + h1*x1 + h2*x2 + h3*x3;
                    Dr[dW + i] = d;
                    __builtin_nontemporal_store(d, &oc[coffW + i]);
                    if (lev == 7) {
                        Dr[2016 + i] = a;
                        __builtin_nontemporal_store(a, &oc[8160 + i]);
                    }
                    else anxt[i] = a;
                }
                __builtin_amdgcn_wave_barrier();
                coffW += half; dW += half; nn = half;
                float* t = acur; acur = anxt; anxt = t;
            }
            // synthesis lev7..4 (in-wave) -> rec4 ends in Cr
            int mS = 32, dS = 1984;
            const float* aprevW = Dr + 2016;
            for (int lev = 7; lev >= 4; --lev) {
                const float h0 = filt[4*lev+0], h1 = filt[4*lev+1],
                            h2 = filt[4*lev+2], h3 = filt[4*lev+3];
                const float g0 = h3, g1 = -h2, g2 = h1, g3 = -h0;
                const int mm = mS - 1;
                float* recW = (lev & 1) ? Br : Cr;
                for (int j = lane; j < mS; j += 64) {
                    const float dj  = Dr[dS + j];
                    const float dj1 = Dr[dS + ((j + 1) & mm)];
                    const float dj2 = Dr[dS + ((j + 2) & mm)];
                    const float aj  = aprevW[j];
                    const float aj1 = aprevW[(j + 1) & mm];
                    const float aj2 = aprevW[(j + 2) & mm];
                    recW[2*j]     = g0*dj  + g2*dj1 + h0*aj  + h2*aj1;
                    recW[2*j + 1] = g1*dj1 + g3*dj2 + h1*aj1 + h3*aj2;
                }
                __builtin_amdgcn_wave_barrier();
                aprevW = recW; mS <<= 1; dS -= mS;
            }
        }
    }
    __syncthreads();   // FULL drain: d0/d1 stores visible before re-read
    // per row: rec4(512) in C[r]

    // ---------------- synthesis levels 3..0 --------------------------------
    // rec[2j]   = g0*d[j]   + g2*d[j+1] + h0*a[j]   + h2*a[j+1]
    // rec[2j+1] = g1*d[j+1] + g3*d[j+2] + h1*a[j+1] + h3*a[j+2]   (mod m)
    {
        const float* aprev[RPB] = { C[0], C[1] };
        int m = 512;
        for (int lev = 3; lev >= 0; --lev) {
            const float h0 = filt[4*lev+0], h1 = filt[4*lev+1],
                        h2 = filt[4*lev+2], h3 = filt[4*lev+3];
            const float g0 = h3, g1 = -h2, g2 = h1, g3 = -h0;
            const int mp = m >> 1, mm = mp - 1;
            const bool last = (lev == 0);
            #pragma unroll
            for (int r = 0; r < RPB; ++r) {
                const float2* a2 = reinterpret_cast<const float2*>(aprev[r]);
                float* rec = (lev & 1) ? B[r] : C[r];
                const float2* __restrict__ d2 =
                    (lev >= 2)
                    ? reinterpret_cast<const float2*>(D[r] + ((lev == 3) ? 1024 : 0))
                    : reinterpret_cast<const float2*>(out + cbase + (row0 + r) * COLS
                                                      + ((lev == 1) ? 4096 : 0));
                float* __restrict__ orc = out + (row0 + r) * COLS;
                for (int p = tid; p < mp; p += TPB) {
                    const float2 dv0 = d2[p];
                    const float2 dv1 = d2[(p + 1) & mm];
                    const float2 av0 = a2[p];
                    const float2 av1 = a2[(p + 1) & mm];
                    const float r0 = g0*dv0.x + g2*dv0.y + h0*av0.x + h2*av0.y;
                    const float r1 = g1*dv0.y + g3*dv1.x + h1*av0.y + h3*av1.x;
                    const float r2 = g0*dv0.y + g2*dv1.x + h0*av0.y + h2*av1.x;
                    const float r3 = g1*dv1.x + g3*dv1.y + h1*av1.x + h3*av1.y;
                    const float4 rv = make_float4(r0, r1, r2, r3);
                    if (last) nt_store4(orc + 4*p, rv);
                    else      reinterpret_cast<float4*>(rec)[p] = rv;
                }
                aprev[r] = rec;
            }
            if (lev) bar_lds();
            m <<= 1;
        }
    }
}

extern "C" void kernel_launch(void* const* d_in, const int* in_sizes, int n_in,
                              void* d_out, int out_size, void* d_ws, size_t ws_size,
                              hipStream_t stream) {
    const float* x       = (const float*)d_in[0];
    const float* scaling = (const float*)d_in[1];
    float* out           = (float*)d_out;
    const int rows = in_sizes[0] / COLS;
    despawn_kernel<<<rows / RPB, TPB, 0, stream>>>(x, scaling, out, rows);
}

// Round 15
// 42.567 us; speedup vs baseline: 1.1045x; 1.1045x over previous
//
#include <hip/hip_runtime.h>

#define COLS   8192
#define LEVELS 8
#define TPB    512

typedef float f4_t __attribute__((ext_vector_type(4)));
typedef float f2_t __attribute__((ext_vector_type(2)));

__device__ __forceinline__ void nt_store4(float* p, const float4 v) {
    f4_t w; w.x = v.x; w.y = v.y; w.z = v.z; w.w = v.w;
    __builtin_nontemporal_store(w, reinterpret_cast<f4_t*>(p));
}
__device__ __forceinline__ void nt_store2(float* p, float a, float b) {
    f2_t w; w.x = a; w.y = b;
    __builtin_nontemporal_store(w, reinterpret_cast<f2_t*>(p));
}

// LDS-only barrier: waits LDS ops, lets global (vmcnt) stores stay in flight.
__device__ __forceinline__ void bar_lds() {
    asm volatile("s_waitcnt lgkmcnt(0)" ::: "memory");
    __builtin_amdgcn_sched_barrier(0);
    __builtin_amdgcn_s_barrier();
    __builtin_amdgcn_sched_barrier(0);
}

// Register lane-blocked analysis level (verified R11): lane l holds
// a[CIN*l .. CIN*l+CIN).  d[i]=h3*a[2i]-h2*a[2i-1]+h1*a[2i-2]-h0*a[2i-3].
#define ANA_LEVEL(CIN, ain, aout, dout, F0, F1, F2, F3)                       \
    {                                                                         \
        const int _src = (l - 1) & 63;                                        \
        const float _m1 = __shfl(ain[(CIN)-1], _src);                         \
        const float _m2 = __shfl(ain[(CIN)-2], _src);                         \
        const float _m3 = __shfl(ain[(CIN)-3], _src);                         \
        dout[0] = (F3)*ain[0] - (F2)*_m1 + (F1)*_m2 - (F0)*_m3;               \
        aout[0] = (F0)*ain[0] + (F1)*_m1 + (F2)*_m2 + (F3)*_m3;               \
        dout[1] = (F3)*ain[2] - (F2)*ain[1] + (F1)*ain[0] - (F0)*_m1;         \
        aout[1] = (F0)*ain[2] + (F1)*ain[1] + (F2)*ain[0] + (F3)*_m1;         \
        _Pragma("unroll")                                                     \
        for (int _j = 2; _j < (CIN)/2; ++_j) {                                \
            dout[_j] = (F3)*ain[2*_j] - (F2)*ain[2*_j-1] + (F1)*ain[2*_j-2] - (F0)*ain[2*_j-3]; \
            aout[_j] = (F0)*ain[2*_j] + (F1)*ain[2*_j-1] + (F2)*ain[2*_j-2] + (F3)*ain[2*_j-3]; \
        }                                                                     \
    }

// Register lane-blocked synthesis level (verified R11).
#define SYN_LEVEL(CD, din, ain, rout, F0, F1, F2, F3)                         \
    {                                                                         \
        const int _src = (l + 1) & 63;                                        \
        const float _d0 = __shfl(din[0], _src);                               \
        const float _d1 = __shfl(din[1], _src);                               \
        const float _a0 = __shfl(ain[0], _src);                               \
        const float _a1 = __shfl(ain[1], _src);                               \
        _Pragma("unroll")                                                     \
        for (int _j = 0; _j < (CD); ++_j) {                                   \
            const float dj  = din[_j];                                        \
            const float dj1 = (_j+1 < (CD)) ? din[_j+1] : _d0;                \
            const float dj2 = (_j+2 < (CD)) ? din[_j+2] : ((_j+1 < (CD)) ? _d0 : _d1); \
            const float aj  = ain[_j];                                        \
            const float aj1 = (_j+1 < (CD)) ? ain[_j+1] : _a0;                \
            const float aj2 = (_j+2 < (CD)) ? ain[_j+2] : ((_j+1 < (CD)) ? _a0 : _a1); \
            rout[2*_j]   = (F3)*dj + (F1)*dj1 + (F0)*aj + (F2)*aj1;           \
            rout[2*_j+1] = -(F2)*dj1 - (F0)*dj2 + (F1)*aj1 + (F3)*aj2;        \
        }                                                                     \
    }

// One block per row. R13 phase chain with: (1) wave-0 tail done entirely in
// registers/shuffles (no LDS round-trips, no wave barriers); (2) d1 kept in
// LDS F so synth1 never touches global; (3) nt stores on never-re-read
// streams. d0 stays cached (re-read in synth0).
__global__ __launch_bounds__(TPB) void despawn_kernel(
    const float* __restrict__ x, const float* __restrict__ scaling,
    float* __restrict__ out, int rows)
{
    __shared__ __align__(16) float B[4096];   // 16 KB  a0/a2 ; rec ping-pong
    __shared__ __align__(16) float C[2048];   // 8 KB   a1/a3 ; rec4 ; rec ping-pong
    __shared__ __align__(16) float D[1536];   // 6 KB   d2[0..1024) | d3[1024..1536)
    __shared__ __align__(16) float F[4096];   // 16 KB  d1 (for synth1)
    __shared__ float filt[LEVELS * 4];

    const int row = blockIdx.x;
    const int tid = threadIdx.x;

    if (tid < LEVELS * 4) filt[tid] = scaling[tid];
    bar_lds();

    const float* __restrict__ xg       = x + (size_t)row * COLS;
    float* __restrict__       out_rec  = out + (size_t)row * COLS;
    float* __restrict__       out_coef = out + (size_t)rows * COLS + (size_t)row * COLS;

    // ---------------- analysis level 0 (global float4, 4 outputs/thread) ----
    {
        const float h0 = filt[0], h1 = filt[1], h2 = filt[2], h3 = filt[3];
        const float g0 = h3, g1 = -h2, g2 = h1, g3 = -h0;
        const float4* __restrict__ xg4 = reinterpret_cast<const float4*>(xg);
        const int q8 = COLS / 8, qm = COLS / 4 - 1;
        for (int i = tid; i < q8; i += TPB) {
            const float4 va = xg4[(2 * i - 1) & qm];
            const float4 vb = xg4[2 * i];
            const float4 vc = xg4[2 * i + 1];
            float4 dv, av;
            dv.x = g0*vb.x + g1*va.w + g2*va.z + g3*va.y;
            av.x = h0*vb.x + h1*va.w + h2*va.z + h3*va.y;
            dv.y = g0*vb.z + g1*vb.y + g2*vb.x + g3*va.w;
            av.y = h0*vb.z + h1*vb.y + h2*vb.x + h3*va.w;
            dv.z = g0*vc.x + g1*vb.w + g2*vb.z + g3*vb.y;
            av.z = h0*vc.x + h1*vb.w + h2*vb.z + h3*vb.y;
            dv.w = g0*vc.z + g1*vc.y + g2*vc.x + g3*vb.w;
            av.w = h0*vc.z + h1*vc.y + h2*vc.x + h3*vb.w;
            reinterpret_cast<float4*>(out_coef)[i] = dv;   // d0: CACHED (re-read)
            reinterpret_cast<float4*>(B)[i]        = av;
        }
        bar_lds();
    }

    // ---------------- analysis levels 1..3 ---------------------------------
    {
        int n = COLS / 2, coff = COLS / 2, dOff = 0;
        float* cur = B;
        float* nxt = C;
        for (int lev = 1; lev <= 3; ++lev) {
            const float h0 = filt[4*lev+0], h1 = filt[4*lev+1],
                        h2 = filt[4*lev+2], h3 = filt[4*lev+3];
            const float g0 = h3, g1 = -h2, g2 = h1, g3 = -h0;
            const int half = n >> 1, qq = half >> 2, qm = (n >> 2) - 1;
            const float4* c4 = reinterpret_cast<const float4*>(cur);
            float* ob = out_coef + coff;
            float4* n4 = reinterpret_cast<float4*>(nxt);
            float4* L4 = (lev == 1) ? reinterpret_cast<float4*>(F)
                                    : reinterpret_cast<float4*>(D + dOff);
            for (int p = tid; p < qq; p += TPB) {
                const float4 va = c4[(2 * p - 1) & qm];
                const float4 vb = c4[2 * p];
                const float4 vc = c4[2 * p + 1];
                float4 dv, av;
                dv.x = g0*vb.x + g1*va.w + g2*va.z + g3*va.y;
                av.x = h0*vb.x + h1*va.w + h2*va.z + h3*va.y;
                dv.y = g0*vb.z + g1*vb.y + g2*vb.x + g3*va.w;
                av.y = h0*vb.z + h1*vb.y + h2*vb.x + h3*va.w;
                dv.z = g0*vc.x + g1*vb.w + g2*vb.z + g3*vb.y;
                av.z = h0*vc.x + h1*vb.w + h2*vb.z + h3*vb.y;
                dv.w = g0*vc.z + g1*vc.y + g2*vc.x + g3*vb.w;
                av.w = h0*vc.z + h1*vc.y + h2*vc.x + h3*vb.w;
                nt_store4(ob + 4*p, dv);   // d1/d2/d3: never re-read from global
                L4[p] = dv;                // LDS copy feeds synthesis
                n4[p] = av;
            }
            bar_lds();
            coff += half;
            if (lev >= 2) dOff += half;
            n = half;
            float* t = cur; cur = nxt; nxt = t;
        }
    }
    // a3(512) in C, d2 in D[0..1024), d3 in D[1024..1536), d1 in F

    // ---------------- wave-0 register tail (lev4..7 + synth7..4) -----------
    if (tid < 64) {
        const int l = tid;
        float a3r[8];
        {
            const float4 v0 = reinterpret_cast<const float4*>(C)[2*l];
            const float4 v1 = reinterpret_cast<const float4*>(C)[2*l+1];
            a3r[0]=v0.x; a3r[1]=v0.y; a3r[2]=v0.z; a3r[3]=v0.w;
            a3r[4]=v1.x; a3r[5]=v1.y; a3r[6]=v1.z; a3r[7]=v1.w;
        }
        float a4r[4], d4r[4];
        ANA_LEVEL(8, a3r, a4r, d4r, filt[16], filt[17], filt[18], filt[19]);
        float a5r[2], d5r[2];
        ANA_LEVEL(4, a4r, a5r, d5r, filt[20], filt[21], filt[22], filt[23]);
        float a6r, d6r;
        {   // lev6: a5 2/lane -> d6,a6 1/lane
            const float F0=filt[24],F1=filt[25],F2=filt[26],F3=filt[27];
            const int s1 = (l-1)&63, s2 = (l-2)&63;
            const float x0 = a5r[0];
            const float x1 = __shfl(a5r[1], s1);
            const float x2 = __shfl(a5r[0], s1);
            const float x3 = __shfl(a5r[1], s2);
            d6r = F3*x0 - F2*x1 + F1*x2 - F0*x3;
            a6r = F0*x0 + F1*x1 + F2*x2 + F3*x3;
        }
        float d7r, apr;
        {   // lev7: a6 1/lane -> d7,ap valid at lanes<32
            const float F0=filt[28],F1=filt[29],F2=filt[30],F3=filt[31];
            const int i2 = 2*l;
            const float x0 = __shfl(a6r, i2 & 63);
            const float x1 = __shfl(a6r, (i2-1)&63);
            const float x2 = __shfl(a6r, (i2-2)&63);
            const float x3 = __shfl(a6r, (i2-3)&63);
            d7r = F3*x0 - F2*x1 + F1*x2 - F0*x3;
            apr = F0*x0 + F1*x1 + F2*x2 + F3*x3;
        }
        // tail coefficient writes (nontemporal; never re-read)
        nt_store4(out_coef + 7680 + 4*l, make_float4(d4r[0],d4r[1],d4r[2],d4r[3]));
        nt_store2(out_coef + 7936 + 2*l, d5r[0], d5r[1]);
        __builtin_nontemporal_store(d6r, &out_coef[8064 + l]);
        if (l < 32) {
            __builtin_nontemporal_store(d7r, &out_coef[8128 + l]);
            __builtin_nontemporal_store(apr, &out_coef[8160 + l]);
        }
        // synthesis lev7..4 in registers
        float rec7;
        {
            const float F0=filt[28],F1=filt[29],F2=filt[30],F3=filt[31];
            const float dj = d7r, dj1 = __shfl(d7r,(l+1)&31), dj2 = __shfl(d7r,(l+2)&31);
            const float aj = apr, aj1 = __shfl(apr,(l+1)&31), aj2 = __shfl(apr,(l+2)&31);
            const float r0 = F3*dj + F1*dj1 + F0*aj + F2*aj1;
            const float r1 = -F2*dj1 - F0*dj2 + F1*aj1 + F3*aj2;
            const float e0 = __shfl(r0, l>>1);
            const float e1 = __shfl(r1, l>>1);
            rec7 = (l & 1) ? e1 : e0;
        }
        float rec6[2];
        {
            const float F0=filt[24],F1=filt[25],F2=filt[26],F3=filt[27];
            const float dj = d6r, dj1 = __shfl(d6r,(l+1)&63), dj2 = __shfl(d6r,(l+2)&63);
            const float aj = rec7, aj1 = __shfl(rec7,(l+1)&63), aj2 = __shfl(rec7,(l+2)&63);
            rec6[0] = F3*dj + F1*dj1 + F0*aj + F2*aj1;
            rec6[1] = -F2*dj1 - F0*dj2 + F1*aj1 + F3*aj2;
        }
        float rec5[4];
        SYN_LEVEL(2, d5r, rec6, rec5, filt[20], filt[21], filt[22], filt[23]);
        float rec4r[8];
        SYN_LEVEL(4, d4r, rec5, rec4r, filt[16], filt[17], filt[18], filt[19]);
        // publish rec4 into C[0..512) (a3 already consumed into registers)
        reinterpret_cast<float4*>(C)[2*l]   = make_float4(rec4r[0],rec4r[1],rec4r[2],rec4r[3]);
        reinterpret_cast<float4*>(C)[2*l+1] = make_float4(rec4r[4],rec4r[5],rec4r[6],rec4r[7]);
    }
    __syncthreads();   // FULL drain: d0 stores must be visible before re-read
    // rec4(512) in C

    // ---------------- synthesis levels 3..0 (all threads, 4 out/thread) -----
#define SYNTH_BODY(d2)                                                        \
    for (int p = tid; p < mp; p += TPB) {                                     \
        const float2 dv0 = (d2)[p];                                           \
        const float2 dv1 = (d2)[(p + 1) & mm];                                \
        const float2 av0 = a2[p];                                             \
        const float2 av1 = a2[(p + 1) & mm];                                  \
        const float r0 = g0*dv0.x + g2*dv0.y + h0*av0.x + h2*av0.y;           \
        const float r1 = g1*dv0.y + g3*dv1.x + h1*av0.y + h3*av1.x;           \
        const float r2 = g0*dv0.y + g2*dv1.x + h0*av0.y + h2*av1.x;           \
        const float r3 = g1*dv1.x + g3*dv1.y + h1*av1.x + h3*av1.y;           \
        const float4 rv = make_float4(r0, r1, r2, r3);                        \
        if (last) nt_store4(out_rec + 4*p, rv);                               \
        else      reinterpret_cast<float4*>(rec)[p] = rv;                     \
    }

    const float* aprev = C;
    int m = 512;
    for (int lev = 3; lev >= 0; --lev) {
        const float h0 = filt[4*lev+0], h1 = filt[4*lev+1],
                    h2 = filt[4*lev+2], h3 = filt[4*lev+3];
        const float g0 = h3, g1 = -h2, g2 = h1, g3 = -h0;
        const int mp = m >> 1, mm = mp - 1;
        const float2* a2 = reinterpret_cast<const float2*>(aprev);
        float* rec = (lev & 1) ? B : C;   // lev3->B lev2->C lev1->B
        const bool last = (lev == 0);
        if (lev >= 2) {
            const float2* dL = reinterpret_cast<const float2*>(D + ((lev == 3) ? 1024 : 0));
            SYNTH_BODY(dL)
        } else if (lev == 1) {
            const float2* dF = reinterpret_cast<const float2*>(F);   // d1 from LDS
            SYNTH_BODY(dF)
        } else {
            const float2* __restrict__ dG = reinterpret_cast<const float2*>(out_coef);
            SYNTH_BODY(dG)
        }
        if (lev) bar_lds();
        aprev = rec; m <<= 1;
    }
#undef SYNTH_BODY
}

extern "C" void kernel_launch(void* const* d_in, const int* in_sizes, int n_in,
                              void* d_out, int out_size, void* d_ws, size_t ws_size,
                              hipStream_t stream) {
    const float* x       = (const float*)d_in[0];
    const float* scaling = (const float*)d_in[1];
    float* out           = (float*)d_out;
    const int rows = in_sizes[0] / COLS;
    despawn_kernel<<<rows, TPB, 0, stream>>>(x, scaling, out, rows);
}